// Round 3
// baseline (297.441 us; speedup 1.0000x reference)
//
#include <hip/hip_runtime.h>

#define D_FEAT 256
#define UNITS  128

#define NBITS  6            // coarse bin = 64 dst nodes
#define BINSZ  64
#define BINCAP 1280         // Binomial(1.6M, 64/100K): mean 1024, sigma 32 -> +8 sigma, cannot overflow
#define MAXNB  1600         // >= ceil(100000/64) = 1563
#define SCHUNK 6400         // edges per scatter block (250 blocks for 1.6M, 1/CU)

typedef __attribute__((ext_vector_type(8))) short short8;   // 8 bf16 (4 VGPRs)
typedef __attribute__((ext_vector_type(4))) float floatx4;

__device__ inline ushort f2bf(float f) {          // fp32 -> bf16, round-nearest-even
    uint u = __float_as_uint(f);
    uint r = u + 0x7FFF + ((u >> 16) & 1);
    return (ushort)(r >> 16);
}

// ---------------------------------------------------------------------------
// One-time prep: wT_bf16[n][k] = bf16(w[k][n]); 128 x 256, 64 KB, L2-resident.
// ---------------------------------------------------------------------------
__global__ __launch_bounds__(256) void wt_prep_kernel(const float* __restrict__ w,
                                                      ushort* __restrict__ wT) {
    int idx = blockIdx.x * 256 + threadIdx.x;     // 32768 threads
    int n = idx >> 8;
    int k = idx & 255;
    wT[n * 256 + k] = f2bf(w[(size_t)k * UNITS + n]);
}

// ---------------------------------------------------------------------------
// h_bf16[M][128] = bf16( x[M][256] @ w[256][128] ) via mfma_f32_16x16x32_bf16.
// v3 (kept): sched_barrier-pinned 16-deep x-load phase + wT staged in
// XOR-swizzled LDS. Took gemm from 81 us / 947 GB/s / VGPR=52 out of top-5.
// ---------------------------------------------------------------------------
__global__ __launch_bounds__(256, 2) void gemm_mfma3_kernel(const float* __restrict__ x,
                                                            const ushort* __restrict__ wT,
                                                            ushort* __restrict__ hb, int M) {
    __shared__ ushort lds_w[128 * 256];   // 64 KB: row n = out-col, 32 x 16B slots, slot^=(n&7)

    const int tid  = threadIdx.x;
    const int wave = tid >> 6;
    const int lane = tid & 63;
    const int quad = lane >> 4;
    const int m16  = lane & 15;

    const int row  = blockIdx.x * 64 + wave * 16 + m16;
    const int rowc = row < M ? row : M - 1;
    const float* xr = x + (size_t)rowc * D_FEAT;

    // ---- phase 0: issue the 16 wT 16B-chunk loads (L2-hot) ----
    short8 wv[16];
    #pragma unroll
    for (int r = 0; r < 16; ++r)
        wv[r] = *(const short8*)(wT + (size_t)(r * 256 + tid) * 8);
    __builtin_amdgcn_sched_barrier(0);

    // ---- phase 1: issue ALL 16 x loads (256 B/lane in flight, HBM) ----
    float4 xv[16];
    #pragma unroll
    for (int s = 0; s < 8; ++s) {
        const float4* p = (const float4*)(xr + s * 32 + quad * 8);
        xv[2 * s]     = p[0];
        xv[2 * s + 1] = p[1];
    }
    __builtin_amdgcn_sched_barrier(0);

    // ---- phase 2: LDS-write wT, XOR-swizzled (waits only the wv loads) ----
    #pragma unroll
    for (int r = 0; r < 16; ++r) {
        int ci = r * 256 + tid;          // 16B chunk index: row = ci>>5, slot = ci&31
        int n  = ci >> 5;
        int ts = (ci & 31) ^ (n & 7);    // swizzled slot
        *(short8*)(lds_w + n * 256 + ts * 8) = wv[r];
    }
    __builtin_amdgcn_sched_barrier(0);

    // ---- phase 3: convert x to bf16 A-fragments (waits the x loads) ----
    short8 afrag[8];
    #pragma unroll
    for (int s = 0; s < 8; ++s) {
        float4 lo = xv[2 * s];
        float4 hi = xv[2 * s + 1];
        union { short8 v; ushort u[8]; } af;
        af.u[0] = f2bf(lo.x); af.u[1] = f2bf(lo.y);
        af.u[2] = f2bf(lo.z); af.u[3] = f2bf(lo.w);
        af.u[4] = f2bf(hi.x); af.u[5] = f2bf(hi.y);
        af.u[6] = f2bf(hi.z); af.u[7] = f2bf(hi.w);
        afrag[s] = af.v;
    }

    __syncthreads();

    // ---- phase 4: MFMA main loop; B-frags via swizzled ds_read_b128 ----
    floatx4 acc[8] = {};
    #pragma unroll
    for (int s = 0; s < 8; ++s) {
        #pragma unroll
        for (int c = 0; c < 8; ++c) {
            int rowb = c * 16 + m16;
            int ts   = (s * 4 + quad) ^ (m16 & 7);
            short8 bfrag = *(const short8*)(lds_w + rowb * 256 + ts * 8);
            acc[c] = __builtin_amdgcn_mfma_f32_16x16x32_bf16(afrag[s], bfrag, acc[c], 0, 0, 0);
        }
    }

    // ---- epilogue: D[row=quad*4+i][col=c*16+m16] -> bf16 ----
    #pragma unroll
    for (int c = 0; c < 8; ++c) {
        #pragma unroll
        for (int i = 0; i < 4; ++i) {
            int r = blockIdx.x * 64 + wave * 16 + quad * 4 + i;
            if (r < M) hb[(size_t)r * UNITS + c * 16 + m16] = f2bf(acc[c][i]);
        }
    }
}

// ---------------------------------------------------------------------------
// Scatter v5: per-block LDS counting sort, then COALESCED staged writes.
// Round-2 lesson: NBITS 6 made per-(block,bin) runs ~4 entries, so the old
// direct scatter emitted 64 isolated 8B stores per wave. Now the chunk is
// sorted by bin in LDS (51 KB) and written out linearly: consecutive lanes
// hit consecutive addresses in same-bin segments -> ~4x fewer write
// transactions, independent of bin width.
// ---------------------------------------------------------------------------
__global__ __launch_bounds__(1024) void coarse_scatter_kernel(const int* __restrict__ src,
                                                              const int* __restrict__ dst,
                                                              const float* __restrict__ vals,
                                                              int* __restrict__ cursor,   // stride 4 ints/bin
                                                              int2* __restrict__ staged,
                                                              int E, int NB) {
    __shared__ int    s_cnt[MAXNB];     // counts, later reused as placement cursor
    __shared__ int    s_start[MAXNB];   // local exclusive offsets
    __shared__ int    s_base[MAXNB];    // global base in staged
    __shared__ int    s_g[256];         // 8-bin group sums
    __shared__ int    s_h[32];          // 64-bin super sums
    __shared__ int2   s_sort[SCHUNK];   // 51.2 KB sorted entries
    __shared__ ushort s_bin[SCHUNK];    // 12.8 KB bin id per sorted pos

    const int tid = threadIdx.x;
    const int e0  = blockIdx.x * SCHUNK;
    const int e1  = min(E, e0 + SCHUNK);
    const int tot = e1 - e0;

    for (int i = tid; i < NB; i += 1024) s_cnt[i] = 0;
    __syncthreads();

    // pass 1: histogram
    for (int e = e0 + tid; e < e1; e += 1024)
        atomicAdd(&s_cnt[dst[e] >> NBITS], 1);
    __syncthreads();

    // three-level exclusive scan over NB (<=1600) bins
    const int NG = (NB + 7) >> 3;       // <=200 groups of 8 bins
    const int NH = (NG + 7) >> 3;       // <=25 supers of 8 groups
    if (tid < NG) {
        int s = 0;
        #pragma unroll
        for (int j = 0; j < 8; ++j) { int bb = tid * 8 + j; if (bb < NB) s += s_cnt[bb]; }
        s_g[tid] = s;
    }
    __syncthreads();
    if (tid < NH) {
        int s = 0;
        #pragma unroll
        for (int j = 0; j < 8; ++j) { int gg = tid * 8 + j; if (gg < NG) s += s_g[gg]; }
        s_h[tid] = s;
    }
    __syncthreads();
    if (tid == 0) {
        int run = 0;
        for (int k = 0; k < NH; ++k) { int c = s_h[k]; s_h[k] = run; run += c; }
    }
    __syncthreads();
    if (tid < NH) {
        int run = s_h[tid];
        #pragma unroll
        for (int j = 0; j < 8; ++j) {
            int gg = tid * 8 + j;
            if (gg < NG) { int c = s_g[gg]; s_g[gg] = run; run += c; }
        }
    }
    __syncthreads();
    if (tid < NG) {
        int run = s_g[tid];
        #pragma unroll
        for (int j = 0; j < 8; ++j) {
            int bb = tid * 8 + j;
            if (bb < NB) {
                int c = s_cnt[bb];
                s_start[bb] = run; run += c;
                s_base[bb]  = (c > 0) ? atomicAdd(&cursor[bb * 4], c) : 0;
            }
        }
    }
    __syncthreads();
    // reuse s_cnt as placement cursor
    for (int i = tid; i < NB; i += 1024) s_cnt[i] = s_start[i];
    __syncthreads();

    // pass 2: place into sorted LDS (global re-read is L1/L2-hot)
    for (int e = e0 + tid; e < e1; e += 1024) {
        int d  = dst[e];
        int bb = d >> NBITS;
        int r  = atomicAdd(&s_cnt[bb], 1);
        s_sort[r] = make_int2(src[e] | ((d & (BINSZ - 1)) << 20), __float_as_int(vals[e]));
        s_bin[r]  = (ushort)bb;
    }
    __syncthreads();

    // pass 3: linear coalesced write-out
    for (int i = tid; i < tot; i += 1024) {
        int bb   = s_bin[i];
        int gpos = s_base[bb] + (i - s_start[bb]);
        if (gpos < BINCAP)
            staged[(size_t)bb * BINCAP + gpos] = s_sort[i];
    }
}

// ---------------------------------------------------------------------------
// Gather v5: quarter-wave gathers. 16 lanes x uint4 (16B) per h-row, so one
// global_load_dwordx4 wave-instruction fetches 4 DIFFERENT rows (1 KB); with
// 4x unroll per quarter: 16 edges = 4 KB in flight per wave (2x v4) at half
// the load-instruction count. Counting sort in LDS unchanged. out stores are
// nontemporal: 51 MB write-once traffic must not evict hb from L2.
// ---------------------------------------------------------------------------
#define ACC8(h, v)                                  \
    a0 += (v) * __uint_as_float((h).x << 16);       \
    a1 += (v) * __uint_as_float((h).x & 0xFFFF0000u); \
    a2 += (v) * __uint_as_float((h).y << 16);       \
    a3 += (v) * __uint_as_float((h).y & 0xFFFF0000u); \
    a4 += (v) * __uint_as_float((h).z << 16);       \
    a5 += (v) * __uint_as_float((h).z & 0xFFFF0000u); \
    a6 += (v) * __uint_as_float((h).w << 16);       \
    a7 += (v) * __uint_as_float((h).w & 0xFFFF0000u);

__global__ __launch_bounds__(512) void gather_sort_kernel(const int* __restrict__ cursor,
                                                          const int2* __restrict__ staged,
                                                          const ushort* __restrict__ hb,
                                                          float* __restrict__ out, int N) {
    __shared__ int2 sraw[BINCAP];
    __shared__ int2 sbuf[BINCAP];
    __shared__ int cnt[BINSZ], ofs[BINSZ], cur[BINSZ];
    __shared__ int gofs[8];

    const int b   = blockIdx.x;
    const int tid = threadIdx.x;

    int n = cursor[b * 4];
    if (n > BINCAP) n = BINCAP;

    for (int i = tid; i < BINSZ; i += 512) cnt[i] = 0;
    __syncthreads();

    const int2* sg = staged + (size_t)b * BINCAP;

    // pass 1: histogram + park raw entries in LDS
    for (int i = tid; i < n; i += 512) {
        int2 e = sg[i];
        sraw[i] = e;
        atomicAdd(&cnt[(e.x >> 20) & (BINSZ - 1)], 1);
    }
    __syncthreads();

    // two-level exclusive prefix scan over cnt[64]
    if (tid < 8) {
        int s = 0;
        #pragma unroll
        for (int j = 0; j < 8; ++j) s += cnt[tid * 8 + j];
        gofs[tid] = s;
    }
    __syncthreads();
    if (tid == 0) {
        int run = 0;
        #pragma unroll
        for (int g = 0; g < 8; ++g) { int c = gofs[g]; gofs[g] = run; run += c; }
    }
    __syncthreads();
    if (tid < 8) {
        int run = gofs[tid];
        #pragma unroll
        for (int j = 0; j < 8; ++j) {
            int d = tid * 8 + j;
            int c = cnt[d];
            ofs[d] = run; cur[d] = run; run += c;
        }
    }
    __syncthreads();

    // pass 2: place sorted (LDS -> LDS)
    for (int i = tid; i < n; i += 512) {
        int2 e = sraw[i];
        int pos = atomicAdd(&cur[(e.x >> 20) & (BINSZ - 1)], 1);
        sbuf[pos] = e;
    }
    __syncthreads();

    // quarter-wave accumulate: executor = wave*4 + quarter (32 per block)
    const int ex = (tid >> 6) * 4 + ((tid & 63) >> 4);
    const int m  = tid & 15;

    #pragma unroll
    for (int r = 0; r < 2; ++r) {
        int d  = r * 32 + ex;
        int dg = b * BINSZ + d;
        if (dg >= N) continue;
        int start = ofs[d];
        int c     = cnt[d];

        float a0 = 0.f, a1 = 0.f, a2 = 0.f, a3 = 0.f;
        float a4 = 0.f, a5 = 0.f, a6 = 0.f, a7 = 0.f;
        int j = 0;
        for (; j + 4 <= c; j += 4) {
            int2 e0 = sbuf[start + j];
            int2 e1 = sbuf[start + j + 1];
            int2 e2 = sbuf[start + j + 2];
            int2 e3 = sbuf[start + j + 3];
            uint4 h0 = *(const uint4*)(hb + (size_t)(e0.x & 0xFFFFF) * UNITS + m * 8);
            uint4 h1 = *(const uint4*)(hb + (size_t)(e1.x & 0xFFFFF) * UNITS + m * 8);
            uint4 h2 = *(const uint4*)(hb + (size_t)(e2.x & 0xFFFFF) * UNITS + m * 8);
            uint4 h3 = *(const uint4*)(hb + (size_t)(e3.x & 0xFFFFF) * UNITS + m * 8);
            float v0 = __int_as_float(e0.y);
            float v1 = __int_as_float(e1.y);
            float v2 = __int_as_float(e2.y);
            float v3 = __int_as_float(e3.y);
            ACC8(h0, v0)
            ACC8(h1, v1)
            ACC8(h2, v2)
            ACC8(h3, v3)
        }
        for (; j < c; ++j) {
            int2 e0 = sbuf[start + j];
            uint4 h0 = *(const uint4*)(hb + (size_t)(e0.x & 0xFFFFF) * UNITS + m * 8);
            float v0 = __int_as_float(e0.y);
            ACC8(h0, v0)
        }

        float* op = out + (size_t)dg * UNITS + m * 8;
        floatx4 r0 = {a0, a1, a2, a3};
        floatx4 r1 = {a4, a5, a6, a7};
        __builtin_nontemporal_store(r0, (floatx4*)op);
        __builtin_nontemporal_store(r1, (floatx4*)(op + 4));
    }
}

extern "C" void kernel_launch(void* const* d_in, const int* in_sizes, int n_in,
                              void* d_out, int out_size, void* d_ws, size_t ws_size,
                              hipStream_t stream) {
    const float* x        = (const float*)d_in[0];
    const float* w        = (const float*)d_in[1];
    const int*   adj_src  = (const int*)d_in[2];
    const int*   adj_dst  = (const int*)d_in[3];
    const float* adj_vals = (const float*)d_in[4];
    float*       out      = (float*)d_out;

    const int M = in_sizes[0] / D_FEAT;   // 100000 nodes
    const int E = in_sizes[2];            // 1600000 edges
    const int NB = (M + BINSZ - 1) >> NBITS;   // 1563 coarse bins

    // Workspace:
    //   hb:     M*128*2           = 25.6 MB
    //   wT:     128*256*2         = 64 KB
    //   cursor: NB*4 ints         = 25 KB
    //   staged: NB*BINCAP*8       = 16.0 MB
    char*   ws  = (char*)d_ws;
    ushort* hb  = (ushort*)ws;
    size_t  off = (size_t)M * UNITS * sizeof(ushort);
    off = (off + 255) & ~(size_t)255;
    ushort* wT  = (ushort*)(ws + off);
    off += (size_t)128 * 256 * sizeof(ushort);
    int*    cursor = (int*)(ws + off);
    off += (size_t)NB * 4 * sizeof(int);
    off = (off + 15) & ~(size_t)15;
    int2*   staged = (int2*)(ws + off);

    hipMemsetAsync(cursor, 0, (size_t)NB * 4 * sizeof(int), stream);

    wt_prep_kernel<<<128, 256, 0, stream>>>(w, wT);

    gemm_mfma3_kernel<<<(M + 63) / 64, 256, 0, stream>>>(x, wT, hb, M);

    const int NSCAT = (E + SCHUNK - 1) / SCHUNK;   // 250 blocks, ~1/CU
    coarse_scatter_kernel<<<NSCAT, 1024, 0, stream>>>(adj_src, adj_dst, adj_vals,
                                                      cursor, staged, E, NB);

    gather_sort_kernel<<<NB, 512, 0, stream>>>(cursor, staged, hb, out, M);
}

// Round 4
// 285.387 us; speedup vs baseline: 1.0422x; 1.0422x over previous
//
#include <hip/hip_runtime.h>

#define D_FEAT 256
#define UNITS  128

#define NBITS  6            // coarse bin = 64 dst nodes
#define BINSZ  64
#define BINCAP 1280         // Binomial(1.6M, 64/100K): mean 1024, sigma 32 -> +8 sigma, cannot overflow
#define MAXNB  1600         // >= ceil(100000/64) = 1563

typedef __attribute__((ext_vector_type(8))) short short8;   // 8 bf16 (4 VGPRs)
typedef __attribute__((ext_vector_type(4))) float floatx4;

__device__ inline ushort f2bf(float f) {          // fp32 -> bf16, round-nearest-even
    uint u = __float_as_uint(f);
    uint r = u + 0x7FFF + ((u >> 16) & 1);
    return (ushort)(r >> 16);
}

// ---------------------------------------------------------------------------
// One-time prep: wT_bf16[n][k] = bf16(w[k][n]); 128 x 256, 64 KB, L2-resident.
// ---------------------------------------------------------------------------
__global__ __launch_bounds__(256) void wt_prep_kernel(const float* __restrict__ w,
                                                      ushort* __restrict__ wT) {
    int idx = blockIdx.x * 256 + threadIdx.x;     // 32768 threads
    int n = idx >> 8;
    int k = idx & 255;
    wT[n * 256 + k] = f2bf(w[(size_t)k * UNITS + n]);
}

// ---------------------------------------------------------------------------
// h_bf16[M][128] = bf16( x[M][256] @ w[256][128] ) via mfma_f32_16x16x32_bf16.
// v3 (kept): sched_barrier-pinned 16-deep x-load phase + wT staged in
// XOR-swizzled LDS. Took gemm from 81 us / 947 GB/s / VGPR=52 out of top-5.
// ---------------------------------------------------------------------------
__global__ __launch_bounds__(256, 2) void gemm_mfma3_kernel(const float* __restrict__ x,
                                                            const ushort* __restrict__ wT,
                                                            ushort* __restrict__ hb, int M) {
    __shared__ ushort lds_w[128 * 256];   // 64 KB: row n = out-col, 32 x 16B slots, slot^=(n&7)

    const int tid  = threadIdx.x;
    const int wave = tid >> 6;
    const int lane = tid & 63;
    const int quad = lane >> 4;
    const int m16  = lane & 15;

    const int row  = blockIdx.x * 64 + wave * 16 + m16;
    const int rowc = row < M ? row : M - 1;
    const float* xr = x + (size_t)rowc * D_FEAT;

    // ---- phase 0: issue the 16 wT 16B-chunk loads (L2-hot) ----
    short8 wv[16];
    #pragma unroll
    for (int r = 0; r < 16; ++r)
        wv[r] = *(const short8*)(wT + (size_t)(r * 256 + tid) * 8);
    __builtin_amdgcn_sched_barrier(0);

    // ---- phase 1: issue ALL 16 x loads (256 B/lane in flight, HBM) ----
    float4 xv[16];
    #pragma unroll
    for (int s = 0; s < 8; ++s) {
        const float4* p = (const float4*)(xr + s * 32 + quad * 8);
        xv[2 * s]     = p[0];
        xv[2 * s + 1] = p[1];
    }
    __builtin_amdgcn_sched_barrier(0);

    // ---- phase 2: LDS-write wT, XOR-swizzled (waits only the wv loads) ----
    #pragma unroll
    for (int r = 0; r < 16; ++r) {
        int ci = r * 256 + tid;          // 16B chunk index: row = ci>>5, slot = ci&31
        int n  = ci >> 5;
        int ts = (ci & 31) ^ (n & 7);    // swizzled slot
        *(short8*)(lds_w + n * 256 + ts * 8) = wv[r];
    }
    __builtin_amdgcn_sched_barrier(0);

    // ---- phase 3: convert x to bf16 A-fragments (waits the x loads) ----
    short8 afrag[8];
    #pragma unroll
    for (int s = 0; s < 8; ++s) {
        float4 lo = xv[2 * s];
        float4 hi = xv[2 * s + 1];
        union { short8 v; ushort u[8]; } af;
        af.u[0] = f2bf(lo.x); af.u[1] = f2bf(lo.y);
        af.u[2] = f2bf(lo.z); af.u[3] = f2bf(lo.w);
        af.u[4] = f2bf(hi.x); af.u[5] = f2bf(hi.y);
        af.u[6] = f2bf(hi.z); af.u[7] = f2bf(hi.w);
        afrag[s] = af.v;
    }

    __syncthreads();

    // ---- phase 4: MFMA main loop; B-frags via swizzled ds_read_b128 ----
    floatx4 acc[8] = {};
    #pragma unroll
    for (int s = 0; s < 8; ++s) {
        #pragma unroll
        for (int c = 0; c < 8; ++c) {
            int rowb = c * 16 + m16;
            int ts   = (s * 4 + quad) ^ (m16 & 7);
            short8 bfrag = *(const short8*)(lds_w + rowb * 256 + ts * 8);
            acc[c] = __builtin_amdgcn_mfma_f32_16x16x32_bf16(afrag[s], bfrag, acc[c], 0, 0, 0);
        }
    }

    // ---- epilogue: D[row=quad*4+i][col=c*16+m16] -> bf16 ----
    #pragma unroll
    for (int c = 0; c < 8; ++c) {
        #pragma unroll
        for (int i = 0; i < 4; ++i) {
            int r = blockIdx.x * 64 + wave * 16 + quad * 4 + i;
            if (r < M) hb[(size_t)r * UNITS + c * 16 + m16] = f2bf(acc[c][i]);
        }
    }
}

// ---------------------------------------------------------------------------
// Coarse scatter (reverted to the round-1/2 direct form — the round-3 LDS
// counting-sort variant cost ~12 us more: 83 KB LDS -> 1 block/CU and three
// edge-stream passes). 256 chunks x 1024 threads, per-chunk LDS histogram,
// one global cursor reservation per (block,bin), then direct staged writes.
// staged entry: {meta = src | (dst&63)<<20, bits(val)}
// ---------------------------------------------------------------------------
__global__ __launch_bounds__(1024) void coarse_scatter_kernel(const int* __restrict__ src,
                                                              const int* __restrict__ dst,
                                                              const float* __restrict__ vals,
                                                              int* __restrict__ cursor,   // stride 4 ints/bin
                                                              int2* __restrict__ staged,
                                                              int E, int NB, int chunk) {
    __shared__ int s_hist[MAXNB];
    __shared__ int s_base[MAXNB];

    const int tid = threadIdx.x;
    const int T   = 1024;
    const int e0 = blockIdx.x * chunk;
    const int e1 = min(E, e0 + chunk);

    for (int i = tid; i < NB; i += T) s_hist[i] = 0;
    __syncthreads();

    for (int e = e0 + tid; e < e1; e += T)
        atomicAdd(&s_hist[dst[e] >> NBITS], 1);
    __syncthreads();

    for (int b = tid; b < NB; b += T) {
        int c = s_hist[b];
        s_base[b] = (c > 0) ? atomicAdd(&cursor[b * 4], c) : 0;
    }
    __syncthreads();
    for (int i = tid; i < NB; i += T) s_hist[i] = 0;   // reuse as rank counter
    __syncthreads();

    for (int e = e0 + tid; e < e1; e += T) {
        int d = dst[e];
        int b = d >> NBITS;
        int r = s_base[b] + atomicAdd(&s_hist[b], 1);
        if (r < BINCAP) {
            int meta = src[e] | ((d & (BINSZ - 1)) << 20);
            staged[(size_t)b * BINCAP + r] = make_int2(meta, __float_as_int(vals[e]));
        }
    }
}

// ---------------------------------------------------------------------------
// Gather v6: quarter-wave uint4 gathers with sched_barrier-PINNED 8-deep load
// batches. Round-3 post-mortem: VGPR_Count=28 proved the compiler serialized
// the intended 4-deep MLP (same signature as the round-0 GEMM, same fix).
// Phase structure per batch: 8 sbuf LDS reads | barrier(0x7) | 8
// global_load_dwordx4 (8 rows = 2 KB in flight per quarter-wave) |
// barrier(0x7) | 96 VALU ops. Mask 0x7 lets ALU cross phases for overlap but
// pins VMEM/DS. NT stores dropped (round 3: +13% WRITE_SIZE from partial-line
// write amplification).
// ---------------------------------------------------------------------------
#define ACC8(h, v)                                  \
    a0 += (v) * __uint_as_float((h).x << 16);       \
    a1 += (v) * __uint_as_float((h).x & 0xFFFF0000u); \
    a2 += (v) * __uint_as_float((h).y << 16);       \
    a3 += (v) * __uint_as_float((h).y & 0xFFFF0000u); \
    a4 += (v) * __uint_as_float((h).z << 16);       \
    a5 += (v) * __uint_as_float((h).z & 0xFFFF0000u); \
    a6 += (v) * __uint_as_float((h).w << 16);       \
    a7 += (v) * __uint_as_float((h).w & 0xFFFF0000u);

__global__ __launch_bounds__(512) void gather_sort_kernel(const int* __restrict__ cursor,
                                                          const int2* __restrict__ staged,
                                                          const ushort* __restrict__ hb,
                                                          float* __restrict__ out, int N) {
    __shared__ int2 sraw[BINCAP];
    __shared__ int2 sbuf[BINCAP];
    __shared__ int cnt[BINSZ], ofs[BINSZ], cur[BINSZ];
    __shared__ int gofs[8];

    const int b   = blockIdx.x;
    const int tid = threadIdx.x;

    int n = cursor[b * 4];
    if (n > BINCAP) n = BINCAP;

    for (int i = tid; i < BINSZ; i += 512) cnt[i] = 0;
    __syncthreads();

    const int2* sg = staged + (size_t)b * BINCAP;

    // pass 1: histogram + park raw entries in LDS
    for (int i = tid; i < n; i += 512) {
        int2 e = sg[i];
        sraw[i] = e;
        atomicAdd(&cnt[(e.x >> 20) & (BINSZ - 1)], 1);
    }
    __syncthreads();

    // two-level exclusive prefix scan over cnt[64]
    if (tid < 8) {
        int s = 0;
        #pragma unroll
        for (int j = 0; j < 8; ++j) s += cnt[tid * 8 + j];
        gofs[tid] = s;
    }
    __syncthreads();
    if (tid == 0) {
        int run = 0;
        #pragma unroll
        for (int g = 0; g < 8; ++g) { int c = gofs[g]; gofs[g] = run; run += c; }
    }
    __syncthreads();
    if (tid < 8) {
        int run = gofs[tid];
        #pragma unroll
        for (int j = 0; j < 8; ++j) {
            int d = tid * 8 + j;
            int c = cnt[d];
            ofs[d] = run; cur[d] = run; run += c;
        }
    }
    __syncthreads();

    // pass 2: place sorted (LDS -> LDS)
    for (int i = tid; i < n; i += 512) {
        int2 e = sraw[i];
        int pos = atomicAdd(&cur[(e.x >> 20) & (BINSZ - 1)], 1);
        sbuf[pos] = e;
    }
    __syncthreads();

    // quarter-wave accumulate: executor = wave*4 + quarter (32 per block)
    const int ex = (tid >> 6) * 4 + ((tid & 63) >> 4);
    const int m  = tid & 15;

    #pragma unroll
    for (int r = 0; r < 2; ++r) {
        int d  = r * 32 + ex;
        int dg = b * BINSZ + d;
        if (dg >= N) continue;
        int start = ofs[d];
        int c     = cnt[d];

        float a0 = 0.f, a1 = 0.f, a2 = 0.f, a3 = 0.f;
        float a4 = 0.f, a5 = 0.f, a6 = 0.f, a7 = 0.f;
        int j = 0;
        for (; j + 8 <= c; j += 8) {
            int2 e0 = sbuf[start + j];
            int2 e1 = sbuf[start + j + 1];
            int2 e2 = sbuf[start + j + 2];
            int2 e3 = sbuf[start + j + 3];
            int2 e4 = sbuf[start + j + 4];
            int2 e5 = sbuf[start + j + 5];
            int2 e6 = sbuf[start + j + 6];
            int2 e7 = sbuf[start + j + 7];
            __builtin_amdgcn_sched_barrier(0x7);   // pin: DS reads above, VMEM below
            uint4 h0 = *(const uint4*)(hb + (size_t)(e0.x & 0xFFFFF) * UNITS + m * 8);
            uint4 h1 = *(const uint4*)(hb + (size_t)(e1.x & 0xFFFFF) * UNITS + m * 8);
            uint4 h2 = *(const uint4*)(hb + (size_t)(e2.x & 0xFFFFF) * UNITS + m * 8);
            uint4 h3 = *(const uint4*)(hb + (size_t)(e3.x & 0xFFFFF) * UNITS + m * 8);
            uint4 h4 = *(const uint4*)(hb + (size_t)(e4.x & 0xFFFFF) * UNITS + m * 8);
            uint4 h5 = *(const uint4*)(hb + (size_t)(e5.x & 0xFFFFF) * UNITS + m * 8);
            uint4 h6 = *(const uint4*)(hb + (size_t)(e6.x & 0xFFFFF) * UNITS + m * 8);
            uint4 h7 = *(const uint4*)(hb + (size_t)(e7.x & 0xFFFFF) * UNITS + m * 8);
            __builtin_amdgcn_sched_barrier(0x7);   // pin: all 8 loads issued before ACC
            float v0 = __int_as_float(e0.y);
            float v1 = __int_as_float(e1.y);
            float v2 = __int_as_float(e2.y);
            float v3 = __int_as_float(e3.y);
            float v4 = __int_as_float(e4.y);
            float v5 = __int_as_float(e5.y);
            float v6 = __int_as_float(e6.y);
            float v7 = __int_as_float(e7.y);
            ACC8(h0, v0)
            ACC8(h1, v1)
            ACC8(h2, v2)
            ACC8(h3, v3)
            ACC8(h4, v4)
            ACC8(h5, v5)
            ACC8(h6, v6)
            ACC8(h7, v7)
        }
        if (j + 4 <= c) {
            int2 e0 = sbuf[start + j];
            int2 e1 = sbuf[start + j + 1];
            int2 e2 = sbuf[start + j + 2];
            int2 e3 = sbuf[start + j + 3];
            __builtin_amdgcn_sched_barrier(0x7);
            uint4 h0 = *(const uint4*)(hb + (size_t)(e0.x & 0xFFFFF) * UNITS + m * 8);
            uint4 h1 = *(const uint4*)(hb + (size_t)(e1.x & 0xFFFFF) * UNITS + m * 8);
            uint4 h2 = *(const uint4*)(hb + (size_t)(e2.x & 0xFFFFF) * UNITS + m * 8);
            uint4 h3 = *(const uint4*)(hb + (size_t)(e3.x & 0xFFFFF) * UNITS + m * 8);
            __builtin_amdgcn_sched_barrier(0x7);
            float v0 = __int_as_float(e0.y);
            float v1 = __int_as_float(e1.y);
            float v2 = __int_as_float(e2.y);
            float v3 = __int_as_float(e3.y);
            ACC8(h0, v0)
            ACC8(h1, v1)
            ACC8(h2, v2)
            ACC8(h3, v3)
            j += 4;
        }
        for (; j < c; ++j) {
            int2 e0 = sbuf[start + j];
            uint4 h0 = *(const uint4*)(hb + (size_t)(e0.x & 0xFFFFF) * UNITS + m * 8);
            float v0 = __int_as_float(e0.y);
            ACC8(h0, v0)
        }

        float* op = out + (size_t)dg * UNITS + m * 8;
        *(floatx4*)op       = (floatx4){a0, a1, a2, a3};
        *(floatx4*)(op + 4) = (floatx4){a4, a5, a6, a7};
    }
}

extern "C" void kernel_launch(void* const* d_in, const int* in_sizes, int n_in,
                              void* d_out, int out_size, void* d_ws, size_t ws_size,
                              hipStream_t stream) {
    const float* x        = (const float*)d_in[0];
    const float* w        = (const float*)d_in[1];
    const int*   adj_src  = (const int*)d_in[2];
    const int*   adj_dst  = (const int*)d_in[3];
    const float* adj_vals = (const float*)d_in[4];
    float*       out      = (float*)d_out;

    const int M = in_sizes[0] / D_FEAT;   // 100000 nodes
    const int E = in_sizes[2];            // 1600000 edges
    const int NB = (M + BINSZ - 1) >> NBITS;   // 1563 coarse bins

    // Workspace:
    //   hb:     M*128*2           = 25.6 MB
    //   wT:     128*256*2         = 64 KB
    //   cursor: NB*4 ints         = 25 KB
    //   staged: NB*BINCAP*8       = 16.0 MB
    char*   ws  = (char*)d_ws;
    ushort* hb  = (ushort*)ws;
    size_t  off = (size_t)M * UNITS * sizeof(ushort);
    off = (off + 255) & ~(size_t)255;
    ushort* wT  = (ushort*)(ws + off);
    off += (size_t)128 * 256 * sizeof(ushort);
    int*    cursor = (int*)(ws + off);
    off += (size_t)NB * 4 * sizeof(int);
    off = (off + 15) & ~(size_t)15;
    int2*   staged = (int2*)(ws + off);

    hipMemsetAsync(cursor, 0, (size_t)NB * 4 * sizeof(int), stream);

    wt_prep_kernel<<<128, 256, 0, stream>>>(w, wT);

    gemm_mfma3_kernel<<<(M + 63) / 64, 256, 0, stream>>>(x, wT, hb, M);

    const int NSCAT = 256;
    const int chunk = (E + NSCAT - 1) / NSCAT;
    coarse_scatter_kernel<<<NSCAT, 1024, 0, stream>>>(adj_src, adj_dst, adj_vals,
                                                      cursor, staged, E, NB, chunk);

    gather_sort_kernel<<<NB, 512, 0, stream>>>(cursor, staged, hb, out, M);
}

// Round 5
// 284.809 us; speedup vs baseline: 1.0444x; 1.0020x over previous
//
#include <hip/hip_runtime.h>

#define D_FEAT 256
#define UNITS  128

#define NBITS  6            // coarse bin = 64 dst nodes
#define BINSZ  64
#define BINCAP 1280         // Binomial(1.6M, 64/100K): mean 1024, sigma 32 -> +8 sigma, cannot overflow
#define MAXNB  1600         // >= ceil(100000/64) = 1563

typedef __attribute__((ext_vector_type(8))) short short8;   // 8 bf16 (4 VGPRs)
typedef __attribute__((ext_vector_type(4))) float floatx4;

__device__ inline ushort f2bf(float f) {          // fp32 -> bf16, round-nearest-even
    uint u = __float_as_uint(f);
    uint r = u + 0x7FFF + ((u >> 16) & 1);
    return (ushort)(r >> 16);
}

// ---------------------------------------------------------------------------
// One-time prep: wT_bf16[n][k] = bf16(w[k][n]); 128 x 256, 64 KB, L2-resident.
// v7: also zeroes the scatter cursor (folds away the hipMemsetAsync dispatch).
// ---------------------------------------------------------------------------
__global__ __launch_bounds__(256) void wt_prep_kernel(const float* __restrict__ w,
                                                      ushort* __restrict__ wT,
                                                      int* __restrict__ cursor, int ncur) {
    int idx = blockIdx.x * 256 + threadIdx.x;     // 32768 threads
    int n = idx >> 8;
    int k = idx & 255;
    wT[n * 256 + k] = f2bf(w[(size_t)k * UNITS + n]);
    if (idx < ncur) cursor[idx] = 0;
}

// ---------------------------------------------------------------------------
// h_bf16[M][128] = bf16( x[M][256] @ w[256][128] ) via mfma_f32_16x16x32_bf16.
// v3 (kept): sched_barrier(0)-pinned 16-deep x-load phase + wT staged in
// XOR-swizzled LDS. Took gemm from 81 us / 947 GB/s / VGPR=52 out of top-5.
// ---------------------------------------------------------------------------
__global__ __launch_bounds__(256, 2) void gemm_mfma3_kernel(const float* __restrict__ x,
                                                            const ushort* __restrict__ wT,
                                                            ushort* __restrict__ hb, int M) {
    __shared__ ushort lds_w[128 * 256];   // 64 KB: row n = out-col, 32 x 16B slots, slot^=(n&7)

    const int tid  = threadIdx.x;
    const int wave = tid >> 6;
    const int lane = tid & 63;
    const int quad = lane >> 4;
    const int m16  = lane & 15;

    const int row  = blockIdx.x * 64 + wave * 16 + m16;
    const int rowc = row < M ? row : M - 1;
    const float* xr = x + (size_t)rowc * D_FEAT;

    // ---- phase 0: issue the 16 wT 16B-chunk loads (L2-hot) ----
    short8 wv[16];
    #pragma unroll
    for (int r = 0; r < 16; ++r)
        wv[r] = *(const short8*)(wT + (size_t)(r * 256 + tid) * 8);
    __builtin_amdgcn_sched_barrier(0);

    // ---- phase 1: issue ALL 16 x loads (256 B/lane in flight, HBM) ----
    float4 xv[16];
    #pragma unroll
    for (int s = 0; s < 8; ++s) {
        const float4* p = (const float4*)(xr + s * 32 + quad * 8);
        xv[2 * s]     = p[0];
        xv[2 * s + 1] = p[1];
    }
    __builtin_amdgcn_sched_barrier(0);

    // ---- phase 2: LDS-write wT, XOR-swizzled (waits only the wv loads) ----
    #pragma unroll
    for (int r = 0; r < 16; ++r) {
        int ci = r * 256 + tid;          // 16B chunk index: row = ci>>5, slot = ci&31
        int n  = ci >> 5;
        int ts = (ci & 31) ^ (n & 7);    // swizzled slot
        *(short8*)(lds_w + n * 256 + ts * 8) = wv[r];
    }
    __builtin_amdgcn_sched_barrier(0);

    // ---- phase 3: convert x to bf16 A-fragments (waits the x loads) ----
    short8 afrag[8];
    #pragma unroll
    for (int s = 0; s < 8; ++s) {
        float4 lo = xv[2 * s];
        float4 hi = xv[2 * s + 1];
        union { short8 v; ushort u[8]; } af;
        af.u[0] = f2bf(lo.x); af.u[1] = f2bf(lo.y);
        af.u[2] = f2bf(lo.z); af.u[3] = f2bf(lo.w);
        af.u[4] = f2bf(hi.x); af.u[5] = f2bf(hi.y);
        af.u[6] = f2bf(hi.z); af.u[7] = f2bf(hi.w);
        afrag[s] = af.v;
    }

    __syncthreads();

    // ---- phase 4: MFMA main loop; B-frags via swizzled ds_read_b128 ----
    floatx4 acc[8] = {};
    #pragma unroll
    for (int s = 0; s < 8; ++s) {
        #pragma unroll
        for (int c = 0; c < 8; ++c) {
            int rowb = c * 16 + m16;
            int ts   = (s * 4 + quad) ^ (m16 & 7);
            short8 bfrag = *(const short8*)(lds_w + rowb * 256 + ts * 8);
            acc[c] = __builtin_amdgcn_mfma_f32_16x16x32_bf16(afrag[s], bfrag, acc[c], 0, 0, 0);
        }
    }

    // ---- epilogue: D[row=quad*4+i][col=c*16+m16] -> bf16 ----
    #pragma unroll
    for (int c = 0; c < 8; ++c) {
        #pragma unroll
        for (int i = 0; i < 4; ++i) {
            int r = blockIdx.x * 64 + wave * 16 + quad * 4 + i;
            if (r < M) hb[(size_t)r * UNITS + c * 16 + m16] = f2bf(acc[c][i]);
        }
    }
}

// ---------------------------------------------------------------------------
// Coarse scatter (round-1/2 direct form). 256 chunks x 1024 threads,
// per-chunk LDS histogram, one global cursor reservation per (block,bin),
// then direct staged writes. staged entry: {meta = src | (dst&63)<<20, val}
// ---------------------------------------------------------------------------
__global__ __launch_bounds__(1024) void coarse_scatter_kernel(const int* __restrict__ src,
                                                              const int* __restrict__ dst,
                                                              const float* __restrict__ vals,
                                                              int* __restrict__ cursor,   // stride 4 ints/bin
                                                              int2* __restrict__ staged,
                                                              int E, int NB, int chunk) {
    __shared__ int s_hist[MAXNB];
    __shared__ int s_base[MAXNB];

    const int tid = threadIdx.x;
    const int T   = 1024;
    const int e0 = blockIdx.x * chunk;
    const int e1 = min(E, e0 + chunk);

    for (int i = tid; i < NB; i += T) s_hist[i] = 0;
    __syncthreads();

    for (int e = e0 + tid; e < e1; e += T)
        atomicAdd(&s_hist[dst[e] >> NBITS], 1);
    __syncthreads();

    for (int b = tid; b < NB; b += T) {
        int c = s_hist[b];
        s_base[b] = (c > 0) ? atomicAdd(&cursor[b * 4], c) : 0;
    }
    __syncthreads();
    for (int i = tid; i < NB; i += T) s_hist[i] = 0;   // reuse as rank counter
    __syncthreads();

    for (int e = e0 + tid; e < e1; e += T) {
        int d = dst[e];
        int b = d >> NBITS;
        int r = s_base[b] + atomicAdd(&s_hist[b], 1);
        if (r < BINCAP) {
            int meta = src[e] | ((d & (BINSZ - 1)) << 20);
            staged[(size_t)b * BINCAP + r] = make_int2(meta, __float_as_int(vals[e]));
        }
    }
}

// ---------------------------------------------------------------------------
// Gather v7: quarter-wave uint4 gathers, 8-deep batches pinned with
// sched_barrier(0) — MASK ZERO. Round-4 post-mortem: mask 0x7 allowed VALU
// (the ACC FMAs) to cross and interleave with the loads, so the allocator
// recycled h-registers (VGPR stayed 36) and the 8-deep MLP never existed.
// Mask 0 is what worked for the GEMM in round 0. With nothing crossing, all
// 8 uint4 loads must be simultaneously live -> vmcnt(7..0) staircase, ~62
// VGPR live set (just under the 64 occupancy step).
// ---------------------------------------------------------------------------
#define ACC8(h, v)                                  \
    a0 += (v) * __uint_as_float((h).x << 16);       \
    a1 += (v) * __uint_as_float((h).x & 0xFFFF0000u); \
    a2 += (v) * __uint_as_float((h).y << 16);       \
    a3 += (v) * __uint_as_float((h).y & 0xFFFF0000u); \
    a4 += (v) * __uint_as_float((h).z << 16);       \
    a5 += (v) * __uint_as_float((h).z & 0xFFFF0000u); \
    a6 += (v) * __uint_as_float((h).w << 16);       \
    a7 += (v) * __uint_as_float((h).w & 0xFFFF0000u);

__global__ __launch_bounds__(512) void gather_sort_kernel(const int* __restrict__ cursor,
                                                          const int2* __restrict__ staged,
                                                          const ushort* __restrict__ hb,
                                                          float* __restrict__ out, int N) {
    __shared__ int2 sraw[BINCAP];
    __shared__ int2 sbuf[BINCAP];
    __shared__ int cnt[BINSZ], ofs[BINSZ], cur[BINSZ];
    __shared__ int gofs[8];

    const int b   = blockIdx.x;
    const int tid = threadIdx.x;

    int n = cursor[b * 4];
    if (n > BINCAP) n = BINCAP;

    for (int i = tid; i < BINSZ; i += 512) cnt[i] = 0;
    __syncthreads();

    const int2* sg = staged + (size_t)b * BINCAP;

    // pass 1: histogram + park raw entries in LDS
    for (int i = tid; i < n; i += 512) {
        int2 e = sg[i];
        sraw[i] = e;
        atomicAdd(&cnt[(e.x >> 20) & (BINSZ - 1)], 1);
    }
    __syncthreads();

    // two-level exclusive prefix scan over cnt[64]
    if (tid < 8) {
        int s = 0;
        #pragma unroll
        for (int j = 0; j < 8; ++j) s += cnt[tid * 8 + j];
        gofs[tid] = s;
    }
    __syncthreads();
    if (tid == 0) {
        int run = 0;
        #pragma unroll
        for (int g = 0; g < 8; ++g) { int c = gofs[g]; gofs[g] = run; run += c; }
    }
    __syncthreads();
    if (tid < 8) {
        int run = gofs[tid];
        #pragma unroll
        for (int j = 0; j < 8; ++j) {
            int d = tid * 8 + j;
            int c = cnt[d];
            ofs[d] = run; cur[d] = run; run += c;
        }
    }
    __syncthreads();

    // pass 2: place sorted (LDS -> LDS)
    for (int i = tid; i < n; i += 512) {
        int2 e = sraw[i];
        int pos = atomicAdd(&cur[(e.x >> 20) & (BINSZ - 1)], 1);
        sbuf[pos] = e;
    }
    __syncthreads();

    // quarter-wave accumulate: executor = wave*4 + quarter (32 per block)
    const int ex = (tid >> 6) * 4 + ((tid & 63) >> 4);
    const int m  = tid & 15;

    #pragma unroll
    for (int r = 0; r < 2; ++r) {
        int d  = r * 32 + ex;
        int dg = b * BINSZ + d;
        if (dg >= N) continue;
        int start = ofs[d];
        int c     = cnt[d];

        float a0 = 0.f, a1 = 0.f, a2 = 0.f, a3 = 0.f;
        float a4 = 0.f, a5 = 0.f, a6 = 0.f, a7 = 0.f;
        int j = 0;
        for (; j + 8 <= c; j += 8) {
            int2 e0 = sbuf[start + j];
            int2 e1 = sbuf[start + j + 1];
            int2 e2 = sbuf[start + j + 2];
            int2 e3 = sbuf[start + j + 3];
            int2 e4 = sbuf[start + j + 4];
            int2 e5 = sbuf[start + j + 5];
            int2 e6 = sbuf[start + j + 6];
            int2 e7 = sbuf[start + j + 7];
            __builtin_amdgcn_sched_barrier(0);     // NOTHING crosses
            uint4 h0 = *(const uint4*)(hb + (size_t)(e0.x & 0xFFFFF) * UNITS + m * 8);
            uint4 h1 = *(const uint4*)(hb + (size_t)(e1.x & 0xFFFFF) * UNITS + m * 8);
            uint4 h2 = *(const uint4*)(hb + (size_t)(e2.x & 0xFFFFF) * UNITS + m * 8);
            uint4 h3 = *(const uint4*)(hb + (size_t)(e3.x & 0xFFFFF) * UNITS + m * 8);
            uint4 h4 = *(const uint4*)(hb + (size_t)(e4.x & 0xFFFFF) * UNITS + m * 8);
            uint4 h5 = *(const uint4*)(hb + (size_t)(e5.x & 0xFFFFF) * UNITS + m * 8);
            uint4 h6 = *(const uint4*)(hb + (size_t)(e6.x & 0xFFFFF) * UNITS + m * 8);
            uint4 h7 = *(const uint4*)(hb + (size_t)(e7.x & 0xFFFFF) * UNITS + m * 8);
            __builtin_amdgcn_sched_barrier(0);     // all 8 loads issued before any ACC
            float v0 = __int_as_float(e0.y);
            float v1 = __int_as_float(e1.y);
            float v2 = __int_as_float(e2.y);
            float v3 = __int_as_float(e3.y);
            float v4 = __int_as_float(e4.y);
            float v5 = __int_as_float(e5.y);
            float v6 = __int_as_float(e6.y);
            float v7 = __int_as_float(e7.y);
            ACC8(h0, v0)
            ACC8(h1, v1)
            ACC8(h2, v2)
            ACC8(h3, v3)
            ACC8(h4, v4)
            ACC8(h5, v5)
            ACC8(h6, v6)
            ACC8(h7, v7)
        }
        if (j + 4 <= c) {
            int2 e0 = sbuf[start + j];
            int2 e1 = sbuf[start + j + 1];
            int2 e2 = sbuf[start + j + 2];
            int2 e3 = sbuf[start + j + 3];
            __builtin_amdgcn_sched_barrier(0);
            uint4 h0 = *(const uint4*)(hb + (size_t)(e0.x & 0xFFFFF) * UNITS + m * 8);
            uint4 h1 = *(const uint4*)(hb + (size_t)(e1.x & 0xFFFFF) * UNITS + m * 8);
            uint4 h2 = *(const uint4*)(hb + (size_t)(e2.x & 0xFFFFF) * UNITS + m * 8);
            uint4 h3 = *(const uint4*)(hb + (size_t)(e3.x & 0xFFFFF) * UNITS + m * 8);
            __builtin_amdgcn_sched_barrier(0);
            float v0 = __int_as_float(e0.y);
            float v1 = __int_as_float(e1.y);
            float v2 = __int_as_float(e2.y);
            float v3 = __int_as_float(e3.y);
            ACC8(h0, v0)
            ACC8(h1, v1)
            ACC8(h2, v2)
            ACC8(h3, v3)
            j += 4;
        }
        for (; j < c; ++j) {
            int2 e0 = sbuf[start + j];
            uint4 h0 = *(const uint4*)(hb + (size_t)(e0.x & 0xFFFFF) * UNITS + m * 8);
            float v0 = __int_as_float(e0.y);
            ACC8(h0, v0)
        }

        float* op = out + (size_t)dg * UNITS + m * 8;
        *(floatx4*)op       = (floatx4){a0, a1, a2, a3};
        *(floatx4*)(op + 4) = (floatx4){a4, a5, a6, a7};
    }
}

extern "C" void kernel_launch(void* const* d_in, const int* in_sizes, int n_in,
                              void* d_out, int out_size, void* d_ws, size_t ws_size,
                              hipStream_t stream) {
    const float* x        = (const float*)d_in[0];
    const float* w        = (const float*)d_in[1];
    const int*   adj_src  = (const int*)d_in[2];
    const int*   adj_dst  = (const int*)d_in[3];
    const float* adj_vals = (const float*)d_in[4];
    float*       out      = (float*)d_out;

    const int M = in_sizes[0] / D_FEAT;   // 100000 nodes
    const int E = in_sizes[2];            // 1600000 edges
    const int NB = (M + BINSZ - 1) >> NBITS;   // 1563 coarse bins

    // Workspace:
    //   hb:     M*128*2           = 25.6 MB
    //   wT:     128*256*2         = 64 KB
    //   cursor: NB*4 ints         = 25 KB
    //   staged: NB*BINCAP*8       = 16.0 MB
    char*   ws  = (char*)d_ws;
    ushort* hb  = (ushort*)ws;
    size_t  off = (size_t)M * UNITS * sizeof(ushort);
    off = (off + 255) & ~(size_t)255;
    ushort* wT  = (ushort*)(ws + off);
    off += (size_t)128 * 256 * sizeof(ushort);
    int*    cursor = (int*)(ws + off);
    off += (size_t)NB * 4 * sizeof(int);
    off = (off + 15) & ~(size_t)15;
    int2*   staged = (int2*)(ws + off);

    wt_prep_kernel<<<128, 256, 0, stream>>>(w, wT, cursor, NB * 4);

    gemm_mfma3_kernel<<<(M + 63) / 64, 256, 0, stream>>>(x, wT, hb, M);

    const int NSCAT = 256;
    const int chunk = (E + NSCAT - 1) / NSCAT;
    coarse_scatter_kernel<<<NSCAT, 1024, 0, stream>>>(adj_src, adj_dst, adj_vals,
                                                      cursor, staged, E, NB, chunk);

    gather_sort_kernel<<<NB, 512, 0, stream>>>(cursor, staged, hb, out, M);
}

// Round 6
// 283.838 us; speedup vs baseline: 1.0479x; 1.0034x over previous
//
#include <hip/hip_runtime.h>

#define D_FEAT 256
#define UNITS  128

#define NBITS  6            // coarse bin = 64 dst nodes
#define BINSZ  64
#define BINCAP 1280         // Binomial(1.6M, 64/100K): mean 1024, sigma 32 -> +8 sigma, cannot overflow
#define MAXNB  1600         // >= ceil(100000/64) = 1563

typedef __attribute__((ext_vector_type(8))) short short8;   // 8 bf16 (4 VGPRs)
typedef __attribute__((ext_vector_type(4))) float floatx4;

__device__ inline ushort f2bf(float f) {          // fp32 -> bf16, round-nearest-even
    uint u = __float_as_uint(f);
    uint r = u + 0x7FFF + ((u >> 16) & 1);
    return (ushort)(r >> 16);
}

// ---------------------------------------------------------------------------
// One-time prep: wT_bf16[n][k] = bf16(w[k][n]); 128 x 256, 64 KB, L2-resident.
// Also zeroes the scatter cursor (folds away the hipMemsetAsync dispatch).
// ---------------------------------------------------------------------------
__global__ __launch_bounds__(256) void wt_prep_kernel(const float* __restrict__ w,
                                                      ushort* __restrict__ wT,
                                                      int* __restrict__ cursor, int ncur) {
    int idx = blockIdx.x * 256 + threadIdx.x;     // 32768 threads
    int n = idx >> 8;
    int k = idx & 255;
    wT[n * 256 + k] = f2bf(w[(size_t)k * UNITS + n]);
    if (idx < ncur) cursor[idx] = 0;
}

// ---------------------------------------------------------------------------
// FUSED gemm ∪ scatter (v8). Round-5 insight: gemm (reads x,w -> hb) and
// scatter (reads adj -> staged) are data-independent but were serialized as
// two dispatches on one stream. One dispatch, blockIdx-routed:
//   blocks [0, NSCAT)        : scatter chunk (256-thread restride of the
//                              proven round-1/2 direct scatter)
//   blocks [NSCAT, NSCAT+Ng) : gemm tile (v3 body, unchanged)
// Scatter blocks first so both streams of work start at t=0. 64 KB LDS
// aliased: gemm uses all of it for wT; scatter uses 12.8 KB for hist/base.
// Gather's ceiling (7.4 TB/s mixed-hierarchy on random 256B gathers,
// invariant across occupancy 34-61% in rounds 2-5) is untouched.
// ---------------------------------------------------------------------------
__global__ __launch_bounds__(256, 2) void gemm_scatter_kernel(
        const float* __restrict__ x, const ushort* __restrict__ wT,
        ushort* __restrict__ hb, int M,
        const int* __restrict__ src, const int* __restrict__ dst,
        const float* __restrict__ vals,
        int* __restrict__ cursor, int2* __restrict__ staged,
        int E, int NB, int chunk, int nscat) {
    __shared__ __align__(16) char smem[65536];
    const int tid = threadIdx.x;

    if ((int)blockIdx.x < nscat) {
        // ---------------- scatter body (256 threads) ----------------
        int* s_hist = (int*)smem;
        int* s_base = s_hist + MAXNB;
        const int T  = 256;
        const int e0 = blockIdx.x * chunk;
        const int e1 = min(E, e0 + chunk);

        for (int i = tid; i < NB; i += T) s_hist[i] = 0;
        __syncthreads();

        for (int e = e0 + tid; e < e1; e += T)
            atomicAdd(&s_hist[dst[e] >> NBITS], 1);
        __syncthreads();

        for (int b = tid; b < NB; b += T) {
            int c = s_hist[b];
            s_base[b] = (c > 0) ? atomicAdd(&cursor[b * 4], c) : 0;
        }
        __syncthreads();
        for (int i = tid; i < NB; i += T) s_hist[i] = 0;   // reuse as rank counter
        __syncthreads();

        for (int e = e0 + tid; e < e1; e += T) {
            int d = dst[e];
            int b = d >> NBITS;
            int r = s_base[b] + atomicAdd(&s_hist[b], 1);
            if (r < BINCAP) {
                int meta = src[e] | ((d & (BINSZ - 1)) << 20);
                staged[(size_t)b * BINCAP + r] = make_int2(meta, __float_as_int(vals[e]));
            }
        }
        return;
    }

    // ---------------- gemm body (v3, bid-shifted) ----------------
    ushort* lds_w = (ushort*)smem;    // 64 KB: row n = out-col, 32 x 16B slots, slot^=(n&7)

    const int bid  = blockIdx.x - nscat;
    const int wave = tid >> 6;
    const int lane = tid & 63;
    const int quad = lane >> 4;
    const int m16  = lane & 15;

    const int row  = bid * 64 + wave * 16 + m16;
    const int rowc = row < M ? row : M - 1;
    const float* xr = x + (size_t)rowc * D_FEAT;

    // ---- phase 0: issue the 16 wT 16B-chunk loads (L2-hot) ----
    short8 wv[16];
    #pragma unroll
    for (int r = 0; r < 16; ++r)
        wv[r] = *(const short8*)(wT + (size_t)(r * 256 + tid) * 8);
    __builtin_amdgcn_sched_barrier(0);

    // ---- phase 1: issue ALL 16 x loads (256 B/lane in flight, HBM) ----
    float4 xv[16];
    #pragma unroll
    for (int s = 0; s < 8; ++s) {
        const float4* p = (const float4*)(xr + s * 32 + quad * 8);
        xv[2 * s]     = p[0];
        xv[2 * s + 1] = p[1];
    }
    __builtin_amdgcn_sched_barrier(0);

    // ---- phase 2: LDS-write wT, XOR-swizzled (waits only the wv loads) ----
    #pragma unroll
    for (int r = 0; r < 16; ++r) {
        int ci = r * 256 + tid;          // 16B chunk index: row = ci>>5, slot = ci&31
        int n  = ci >> 5;
        int ts = (ci & 31) ^ (n & 7);    // swizzled slot
        *(short8*)(lds_w + n * 256 + ts * 8) = wv[r];
    }
    __builtin_amdgcn_sched_barrier(0);

    // ---- phase 3: convert x to bf16 A-fragments (waits the x loads) ----
    short8 afrag[8];
    #pragma unroll
    for (int s = 0; s < 8; ++s) {
        float4 lo = xv[2 * s];
        float4 hi = xv[2 * s + 1];
        union { short8 v; ushort u[8]; } af;
        af.u[0] = f2bf(lo.x); af.u[1] = f2bf(lo.y);
        af.u[2] = f2bf(lo.z); af.u[3] = f2bf(lo.w);
        af.u[4] = f2bf(hi.x); af.u[5] = f2bf(hi.y);
        af.u[6] = f2bf(hi.z); af.u[7] = f2bf(hi.w);
        afrag[s] = af.v;
    }

    __syncthreads();

    // ---- phase 4: MFMA main loop; B-frags via swizzled ds_read_b128 ----
    floatx4 acc[8] = {};
    #pragma unroll
    for (int s = 0; s < 8; ++s) {
        #pragma unroll
        for (int c = 0; c < 8; ++c) {
            int rowb = c * 16 + m16;
            int ts   = (s * 4 + quad) ^ (m16 & 7);
            short8 bfrag = *(const short8*)(lds_w + rowb * 256 + ts * 8);
            acc[c] = __builtin_amdgcn_mfma_f32_16x16x32_bf16(afrag[s], bfrag, acc[c], 0, 0, 0);
        }
    }

    // ---- epilogue: D[row=quad*4+i][col=c*16+m16] -> bf16 ----
    #pragma unroll
    for (int c = 0; c < 8; ++c) {
        #pragma unroll
        for (int i = 0; i < 4; ++i) {
            int r = bid * 64 + wave * 16 + quad * 4 + i;
            if (r < M) hb[(size_t)r * UNITS + c * 16 + m16] = f2bf(acc[c][i]);
        }
    }
}

// ---------------------------------------------------------------------------
// Gather v7 (kept — at its mixed-hierarchy bandwidth ceiling: 63-66 us across
// occupancy 34-61% and four pipeline structures in rounds 2-5).
// ---------------------------------------------------------------------------
#define ACC8(h, v)                                  \
    a0 += (v) * __uint_as_float((h).x << 16);       \
    a1 += (v) * __uint_as_float((h).x & 0xFFFF0000u); \
    a2 += (v) * __uint_as_float((h).y << 16);       \
    a3 += (v) * __uint_as_float((h).y & 0xFFFF0000u); \
    a4 += (v) * __uint_as_float((h).z << 16);       \
    a5 += (v) * __uint_as_float((h).z & 0xFFFF0000u); \
    a6 += (v) * __uint_as_float((h).w << 16);       \
    a7 += (v) * __uint_as_float((h).w & 0xFFFF0000u);

__global__ __launch_bounds__(512) void gather_sort_kernel(const int* __restrict__ cursor,
                                                          const int2* __restrict__ staged,
                                                          const ushort* __restrict__ hb,
                                                          float* __restrict__ out, int N) {
    __shared__ int2 sraw[BINCAP];
    __shared__ int2 sbuf[BINCAP];
    __shared__ int cnt[BINSZ], ofs[BINSZ], cur[BINSZ];
    __shared__ int gofs[8];

    const int b   = blockIdx.x;
    const int tid = threadIdx.x;

    int n = cursor[b * 4];
    if (n > BINCAP) n = BINCAP;

    for (int i = tid; i < BINSZ; i += 512) cnt[i] = 0;
    __syncthreads();

    const int2* sg = staged + (size_t)b * BINCAP;

    // pass 1: histogram + park raw entries in LDS
    for (int i = tid; i < n; i += 512) {
        int2 e = sg[i];
        sraw[i] = e;
        atomicAdd(&cnt[(e.x >> 20) & (BINSZ - 1)], 1);
    }
    __syncthreads();

    // two-level exclusive prefix scan over cnt[64]
    if (tid < 8) {
        int s = 0;
        #pragma unroll
        for (int j = 0; j < 8; ++j) s += cnt[tid * 8 + j];
        gofs[tid] = s;
    }
    __syncthreads();
    if (tid == 0) {
        int run = 0;
        #pragma unroll
        for (int g = 0; g < 8; ++g) { int c = gofs[g]; gofs[g] = run; run += c; }
    }
    __syncthreads();
    if (tid < 8) {
        int run = gofs[tid];
        #pragma unroll
        for (int j = 0; j < 8; ++j) {
            int d = tid * 8 + j;
            int c = cnt[d];
            ofs[d] = run; cur[d] = run; run += c;
        }
    }
    __syncthreads();

    // pass 2: place sorted (LDS -> LDS)
    for (int i = tid; i < n; i += 512) {
        int2 e = sraw[i];
        int pos = atomicAdd(&cur[(e.x >> 20) & (BINSZ - 1)], 1);
        sbuf[pos] = e;
    }
    __syncthreads();

    // quarter-wave accumulate: executor = wave*4 + quarter (32 per block)
    const int ex = (tid >> 6) * 4 + ((tid & 63) >> 4);
    const int m  = tid & 15;

    #pragma unroll
    for (int r = 0; r < 2; ++r) {
        int d  = r * 32 + ex;
        int dg = b * BINSZ + d;
        if (dg >= N) continue;
        int start = ofs[d];
        int c     = cnt[d];

        float a0 = 0.f, a1 = 0.f, a2 = 0.f, a3 = 0.f;
        float a4 = 0.f, a5 = 0.f, a6 = 0.f, a7 = 0.f;
        int j = 0;
        for (; j + 8 <= c; j += 8) {
            int2 e0 = sbuf[start + j];
            int2 e1 = sbuf[start + j + 1];
            int2 e2 = sbuf[start + j + 2];
            int2 e3 = sbuf[start + j + 3];
            int2 e4 = sbuf[start + j + 4];
            int2 e5 = sbuf[start + j + 5];
            int2 e6 = sbuf[start + j + 6];
            int2 e7 = sbuf[start + j + 7];
            __builtin_amdgcn_sched_barrier(0);     // NOTHING crosses
            uint4 h0 = *(const uint4*)(hb + (size_t)(e0.x & 0xFFFFF) * UNITS + m * 8);
            uint4 h1 = *(const uint4*)(hb + (size_t)(e1.x & 0xFFFFF) * UNITS + m * 8);
            uint4 h2 = *(const uint4*)(hb + (size_t)(e2.x & 0xFFFFF) * UNITS + m * 8);
            uint4 h3 = *(const uint4*)(hb + (size_t)(e3.x & 0xFFFFF) * UNITS + m * 8);
            uint4 h4 = *(const uint4*)(hb + (size_t)(e4.x & 0xFFFFF) * UNITS + m * 8);
            uint4 h5 = *(const uint4*)(hb + (size_t)(e5.x & 0xFFFFF) * UNITS + m * 8);
            uint4 h6 = *(const uint4*)(hb + (size_t)(e6.x & 0xFFFFF) * UNITS + m * 8);
            uint4 h7 = *(const uint4*)(hb + (size_t)(e7.x & 0xFFFFF) * UNITS + m * 8);
            __builtin_amdgcn_sched_barrier(0);     // all 8 loads issued before any ACC
            float v0 = __int_as_float(e0.y);
            float v1 = __int_as_float(e1.y);
            float v2 = __int_as_float(e2.y);
            float v3 = __int_as_float(e3.y);
            float v4 = __int_as_float(e4.y);
            float v5 = __int_as_float(e5.y);
            float v6 = __int_as_float(e6.y);
            float v7 = __int_as_float(e7.y);
            ACC8(h0, v0)
            ACC8(h1, v1)
            ACC8(h2, v2)
            ACC8(h3, v3)
            ACC8(h4, v4)
            ACC8(h5, v5)
            ACC8(h6, v6)
            ACC8(h7, v7)
        }
        if (j + 4 <= c) {
            int2 e0 = sbuf[start + j];
            int2 e1 = sbuf[start + j + 1];
            int2 e2 = sbuf[start + j + 2];
            int2 e3 = sbuf[start + j + 3];
            __builtin_amdgcn_sched_barrier(0);
            uint4 h0 = *(const uint4*)(hb + (size_t)(e0.x & 0xFFFFF) * UNITS + m * 8);
            uint4 h1 = *(const uint4*)(hb + (size_t)(e1.x & 0xFFFFF) * UNITS + m * 8);
            uint4 h2 = *(const uint4*)(hb + (size_t)(e2.x & 0xFFFFF) * UNITS + m * 8);
            uint4 h3 = *(const uint4*)(hb + (size_t)(e3.x & 0xFFFFF) * UNITS + m * 8);
            __builtin_amdgcn_sched_barrier(0);
            float v0 = __int_as_float(e0.y);
            float v1 = __int_as_float(e1.y);
            float v2 = __int_as_float(e2.y);
            float v3 = __int_as_float(e3.y);
            ACC8(h0, v0)
            ACC8(h1, v1)
            ACC8(h2, v2)
            ACC8(h3, v3)
            j += 4;
        }
        for (; j < c; ++j) {
            int2 e0 = sbuf[start + j];
            uint4 h0 = *(const uint4*)(hb + (size_t)(e0.x & 0xFFFFF) * UNITS + m * 8);
            float v0 = __int_as_float(e0.y);
            ACC8(h0, v0)
        }

        float* op = out + (size_t)dg * UNITS + m * 8;
        *(floatx4*)op       = (floatx4){a0, a1, a2, a3};
        *(floatx4*)(op + 4) = (floatx4){a4, a5, a6, a7};
    }
}

extern "C" void kernel_launch(void* const* d_in, const int* in_sizes, int n_in,
                              void* d_out, int out_size, void* d_ws, size_t ws_size,
                              hipStream_t stream) {
    const float* x        = (const float*)d_in[0];
    const float* w        = (const float*)d_in[1];
    const int*   adj_src  = (const int*)d_in[2];
    const int*   adj_dst  = (const int*)d_in[3];
    const float* adj_vals = (const float*)d_in[4];
    float*       out      = (float*)d_out;

    const int M = in_sizes[0] / D_FEAT;   // 100000 nodes
    const int E = in_sizes[2];            // 1600000 edges
    const int NB = (M + BINSZ - 1) >> NBITS;   // 1563 coarse bins

    // Workspace:
    //   hb:     M*128*2           = 25.6 MB
    //   wT:     128*256*2         = 64 KB
    //   cursor: NB*4 ints         = 25 KB
    //   staged: NB*BINCAP*8       = 16.0 MB
    char*   ws  = (char*)d_ws;
    ushort* hb  = (ushort*)ws;
    size_t  off = (size_t)M * UNITS * sizeof(ushort);
    off = (off + 255) & ~(size_t)255;
    ushort* wT  = (ushort*)(ws + off);
    off += (size_t)128 * 256 * sizeof(ushort);
    int*    cursor = (int*)(ws + off);
    off += (size_t)NB * 4 * sizeof(int);
    off = (off + 15) & ~(size_t)15;
    int2*   staged = (int2*)(ws + off);

    wt_prep_kernel<<<128, 256, 0, stream>>>(w, wT, cursor, NB * 4);

    const int NSCAT = 256;
    const int chunk = (E + NSCAT - 1) / NSCAT;
    const int NGEMM = (M + 63) / 64;
    gemm_scatter_kernel<<<NSCAT + NGEMM, 256, 0, stream>>>(
        x, wT, hb, M, adj_src, adj_dst, adj_vals, cursor, staged, E, NB, chunk, NSCAT);

    gather_sort_kernel<<<NB, 512, 0, stream>>>(cursor, staged, hb, out, M);
}

// Round 7
// 282.463 us; speedup vs baseline: 1.0530x; 1.0049x over previous
//
#include <hip/hip_runtime.h>

#define D_FEAT 256
#define UNITS  128

#define NBITS  7            // coarse bin = 128 dst (round-7: back from 6 — scatter run length doubles)
#define BINSZ  128
#define BINCAP 2432         // Poisson(2048) + 8.5 sigma — cannot overflow for random dst
#define MAXNB  800          // >= ceil(100000/128) = 782

typedef __attribute__((ext_vector_type(8))) short short8;   // 8 bf16 (4 VGPRs)
typedef __attribute__((ext_vector_type(4))) float floatx4;

__device__ inline ushort f2bf(float f) {          // fp32 -> bf16, round-nearest-even
    uint u = __float_as_uint(f);
    uint r = u + 0x7FFF + ((u >> 16) & 1);
    return (ushort)(r >> 16);
}

// ---------------------------------------------------------------------------
// One-time prep: wT_bf16[n][k] = bf16(w[k][n]); 128 x 256, 64 KB, L2-resident.
// Also zeroes the scatter cursor (folds away the hipMemsetAsync dispatch).
// ---------------------------------------------------------------------------
__global__ __launch_bounds__(256) void wt_prep_kernel(const float* __restrict__ w,
                                                      ushort* __restrict__ wT,
                                                      int* __restrict__ cursor, int ncur) {
    int idx = blockIdx.x * 256 + threadIdx.x;     // 32768 threads
    int n = idx >> 8;
    int k = idx & 255;
    wT[n * 256 + k] = f2bf(w[(size_t)k * UNITS + n]);
    if (idx < ncur) cursor[idx] = 0;
}

// ---------------------------------------------------------------------------
// GEMM v4: v3's proven per-wave body (sched_barrier(0)-pinned 16-deep x-load
// phase, XOR-swizzled wT in LDS) at 512 threads / 128 rows per block.
// Round-6 de-fusion + occupancy fix: v3 ran 2 blocks x 4 waves = 8 waves/CU
// (25%); 8-wave blocks give 16 waves/CU at the SAME 64 KB LDS (2 blocks =
// 128 KB < 160) and the same x traffic. launch_bounds(512,4): 4 waves/EU
// -> <=128 VGPR cap (v3 body measured 88).
// ---------------------------------------------------------------------------
__global__ __launch_bounds__(512, 4) void gemm_mfma4_kernel(const float* __restrict__ x,
                                                            const ushort* __restrict__ wT,
                                                            ushort* __restrict__ hb, int M) {
    __shared__ ushort lds_w[128 * 256];   // 64 KB: row n = out-col, 32 x 16B slots, slot^=(n&7)

    const int tid  = threadIdx.x;
    const int wave = tid >> 6;            // 0..7
    const int lane = tid & 63;
    const int quad = lane >> 4;
    const int m16  = lane & 15;

    const int row  = blockIdx.x * 128 + wave * 16 + m16;
    const int rowc = row < M ? row : M - 1;
    const float* xr = x + (size_t)rowc * D_FEAT;

    // ---- phase 0: issue the 8 wT 16B-chunk loads (L2-hot) ----
    short8 wv[8];
    #pragma unroll
    for (int r = 0; r < 8; ++r)
        wv[r] = *(const short8*)(wT + (size_t)(r * 512 + tid) * 8);
    __builtin_amdgcn_sched_barrier(0);

    // ---- phase 1: issue ALL 16 x loads (256 B/lane in flight, HBM) ----
    float4 xv[16];
    #pragma unroll
    for (int s = 0; s < 8; ++s) {
        const float4* p = (const float4*)(xr + s * 32 + quad * 8);
        xv[2 * s]     = p[0];
        xv[2 * s + 1] = p[1];
    }
    __builtin_amdgcn_sched_barrier(0);

    // ---- phase 2: LDS-write wT, XOR-swizzled (waits only the wv loads) ----
    #pragma unroll
    for (int r = 0; r < 8; ++r) {
        int ci = r * 512 + tid;          // 16B chunk index: row = ci>>5, slot = ci&31
        int n  = ci >> 5;
        int ts = (ci & 31) ^ (n & 7);    // swizzled slot
        *(short8*)(lds_w + n * 256 + ts * 8) = wv[r];
    }
    __builtin_amdgcn_sched_barrier(0);

    // ---- phase 3: convert x to bf16 A-fragments (waits the x loads) ----
    short8 afrag[8];
    #pragma unroll
    for (int s = 0; s < 8; ++s) {
        float4 lo = xv[2 * s];
        float4 hi = xv[2 * s + 1];
        union { short8 v; ushort u[8]; } af;
        af.u[0] = f2bf(lo.x); af.u[1] = f2bf(lo.y);
        af.u[2] = f2bf(lo.z); af.u[3] = f2bf(lo.w);
        af.u[4] = f2bf(hi.x); af.u[5] = f2bf(hi.y);
        af.u[6] = f2bf(hi.z); af.u[7] = f2bf(hi.w);
        afrag[s] = af.v;
    }

    __syncthreads();

    // ---- phase 4: MFMA main loop; B-frags via swizzled ds_read_b128 ----
    floatx4 acc[8] = {};
    #pragma unroll
    for (int s = 0; s < 8; ++s) {
        #pragma unroll
        for (int c = 0; c < 8; ++c) {
            int rowb = c * 16 + m16;
            int ts   = (s * 4 + quad) ^ (m16 & 7);
            short8 bfrag = *(const short8*)(lds_w + rowb * 256 + ts * 8);
            acc[c] = __builtin_amdgcn_mfma_f32_16x16x32_bf16(afrag[s], bfrag, acc[c], 0, 0, 0);
        }
    }

    // ---- epilogue: D[row=quad*4+i][col=c*16+m16] -> bf16 ----
    #pragma unroll
    for (int c = 0; c < 8; ++c) {
        #pragma unroll
        for (int i = 0; i < 4; ++i) {
            int r = blockIdx.x * 128 + wave * 16 + quad * 4 + i;
            if (r < M) hb[(size_t)r * UNITS + c * 16 + m16] = f2bf(acc[c][i]);
        }
    }
}

// ---------------------------------------------------------------------------
// Coarse scatter (round-1 direct form, NBITS 7): 256 chunks x 1024 threads,
// per-chunk LDS histogram, one cursor reservation per (block,bin), direct
// staged writes. 128-dst bins -> ~8-entry (64 B) runs per (block,bin).
// staged entry: {meta = src | (dst&127)<<20, bits(val)}
// ---------------------------------------------------------------------------
__global__ __launch_bounds__(1024) void coarse_scatter_kernel(const int* __restrict__ src,
                                                              const int* __restrict__ dst,
                                                              const float* __restrict__ vals,
                                                              int* __restrict__ cursor,   // stride 4 ints/bin
                                                              int2* __restrict__ staged,
                                                              int E, int NB, int chunk) {
    __shared__ int s_hist[MAXNB];
    __shared__ int s_base[MAXNB];

    const int tid = threadIdx.x;
    const int T   = 1024;
    const int e0 = blockIdx.x * chunk;
    const int e1 = min(E, e0 + chunk);

    for (int i = tid; i < NB; i += T) s_hist[i] = 0;
    __syncthreads();

    for (int e = e0 + tid; e < e1; e += T)
        atomicAdd(&s_hist[dst[e] >> NBITS], 1);
    __syncthreads();

    for (int b = tid; b < NB; b += T) {
        int c = s_hist[b];
        s_base[b] = (c > 0) ? atomicAdd(&cursor[b * 4], c) : 0;
    }
    __syncthreads();
    for (int i = tid; i < NB; i += T) s_hist[i] = 0;   // reuse as rank counter
    __syncthreads();

    for (int e = e0 + tid; e < e1; e += T) {
        int d = dst[e];
        int b = d >> NBITS;
        int r = s_base[b] + atomicAdd(&s_hist[b], 1);
        if (r < BINCAP) {
            int meta = src[e] | ((d & (BINSZ - 1)) << 20);
            staged[(size_t)b * BINCAP + r] = make_int2(meta, __float_as_int(vals[e]));
        }
    }
}

// ---------------------------------------------------------------------------
// Gather (v7 body at BINSZ=128): one 512-thread block per 128-dst bin.
// 40.5 KB LDS -> 3 blocks/CU = 24 waves/CU (rounds 2-5 showed gather
// throughput-invariant across occupancy 34-61%, so 782 blocks is enough).
// Quarter-wave uint4 gathers, 8-deep batches pinned with sched_barrier(0).
// ---------------------------------------------------------------------------
#define ACC8(h, v)                                  \
    a0 += (v) * __uint_as_float((h).x << 16);       \
    a1 += (v) * __uint_as_float((h).x & 0xFFFF0000u); \
    a2 += (v) * __uint_as_float((h).y << 16);       \
    a3 += (v) * __uint_as_float((h).y & 0xFFFF0000u); \
    a4 += (v) * __uint_as_float((h).z << 16);       \
    a5 += (v) * __uint_as_float((h).z & 0xFFFF0000u); \
    a6 += (v) * __uint_as_float((h).w << 16);       \
    a7 += (v) * __uint_as_float((h).w & 0xFFFF0000u);

__global__ __launch_bounds__(512) void gather_sort_kernel(const int* __restrict__ cursor,
                                                          const int2* __restrict__ staged,
                                                          const ushort* __restrict__ hb,
                                                          float* __restrict__ out, int N) {
    __shared__ int2 sraw[BINCAP];
    __shared__ int2 sbuf[BINCAP];
    __shared__ int cnt[BINSZ], ofs[BINSZ], cur[BINSZ];
    __shared__ int gofs[16];

    const int b   = blockIdx.x;
    const int tid = threadIdx.x;

    int n = cursor[b * 4];
    if (n > BINCAP) n = BINCAP;

    for (int i = tid; i < BINSZ; i += 512) cnt[i] = 0;
    __syncthreads();

    const int2* sg = staged + (size_t)b * BINCAP;

    // pass 1: histogram + park raw entries in LDS
    for (int i = tid; i < n; i += 512) {
        int2 e = sg[i];
        sraw[i] = e;
        atomicAdd(&cnt[(e.x >> 20) & (BINSZ - 1)], 1);
    }
    __syncthreads();

    // two-level exclusive prefix scan over cnt[128]
    if (tid < 16) {
        int s = 0;
        #pragma unroll
        for (int j = 0; j < 8; ++j) s += cnt[tid * 8 + j];
        gofs[tid] = s;
    }
    __syncthreads();
    if (tid == 0) {
        int run = 0;
        #pragma unroll
        for (int g = 0; g < 16; ++g) { int c = gofs[g]; gofs[g] = run; run += c; }
    }
    __syncthreads();
    if (tid < 16) {
        int run = gofs[tid];
        #pragma unroll
        for (int j = 0; j < 8; ++j) {
            int d = tid * 8 + j;
            int c = cnt[d];
            ofs[d] = run; cur[d] = run; run += c;
        }
    }
    __syncthreads();

    // pass 2: place sorted (LDS -> LDS)
    for (int i = tid; i < n; i += 512) {
        int2 e = sraw[i];
        int pos = atomicAdd(&cur[(e.x >> 20) & (BINSZ - 1)], 1);
        sbuf[pos] = e;
    }
    __syncthreads();

    // quarter-wave accumulate: executor = wave*4 + quarter (32 per block)
    const int ex = (tid >> 6) * 4 + ((tid & 63) >> 4);
    const int m  = tid & 15;

    #pragma unroll
    for (int r = 0; r < 4; ++r) {
        int d  = r * 32 + ex;
        int dg = b * BINSZ + d;
        if (dg >= N) continue;
        int start = ofs[d];
        int c     = cnt[d];

        float a0 = 0.f, a1 = 0.f, a2 = 0.f, a3 = 0.f;
        float a4 = 0.f, a5 = 0.f, a6 = 0.f, a7 = 0.f;
        int j = 0;
        for (; j + 8 <= c; j += 8) {
            int2 e0 = sbuf[start + j];
            int2 e1 = sbuf[start + j + 1];
            int2 e2 = sbuf[start + j + 2];
            int2 e3 = sbuf[start + j + 3];
            int2 e4 = sbuf[start + j + 4];
            int2 e5 = sbuf[start + j + 5];
            int2 e6 = sbuf[start + j + 6];
            int2 e7 = sbuf[start + j + 7];
            __builtin_amdgcn_sched_barrier(0);     // NOTHING crosses
            uint4 h0 = *(const uint4*)(hb + (size_t)(e0.x & 0xFFFFF) * UNITS + m * 8);
            uint4 h1 = *(const uint4*)(hb + (size_t)(e1.x & 0xFFFFF) * UNITS + m * 8);
            uint4 h2 = *(const uint4*)(hb + (size_t)(e2.x & 0xFFFFF) * UNITS + m * 8);
            uint4 h3 = *(const uint4*)(hb + (size_t)(e3.x & 0xFFFFF) * UNITS + m * 8);
            uint4 h4 = *(const uint4*)(hb + (size_t)(e4.x & 0xFFFFF) * UNITS + m * 8);
            uint4 h5 = *(const uint4*)(hb + (size_t)(e5.x & 0xFFFFF) * UNITS + m * 8);
            uint4 h6 = *(const uint4*)(hb + (size_t)(e6.x & 0xFFFFF) * UNITS + m * 8);
            uint4 h7 = *(const uint4*)(hb + (size_t)(e7.x & 0xFFFFF) * UNITS + m * 8);
            __builtin_amdgcn_sched_barrier(0);     // all 8 loads issued before any ACC
            float v0 = __int_as_float(e0.y);
            float v1 = __int_as_float(e1.y);
            float v2 = __int_as_float(e2.y);
            float v3 = __int_as_float(e3.y);
            float v4 = __int_as_float(e4.y);
            float v5 = __int_as_float(e5.y);
            float v6 = __int_as_float(e6.y);
            float v7 = __int_as_float(e7.y);
            ACC8(h0, v0)
            ACC8(h1, v1)
            ACC8(h2, v2)
            ACC8(h3, v3)
            ACC8(h4, v4)
            ACC8(h5, v5)
            ACC8(h6, v6)
            ACC8(h7, v7)
        }
        if (j + 4 <= c) {
            int2 e0 = sbuf[start + j];
            int2 e1 = sbuf[start + j + 1];
            int2 e2 = sbuf[start + j + 2];
            int2 e3 = sbuf[start + j + 3];
            __builtin_amdgcn_sched_barrier(0);
            uint4 h0 = *(const uint4*)(hb + (size_t)(e0.x & 0xFFFFF) * UNITS + m * 8);
            uint4 h1 = *(const uint4*)(hb + (size_t)(e1.x & 0xFFFFF) * UNITS + m * 8);
            uint4 h2 = *(const uint4*)(hb + (size_t)(e2.x & 0xFFFFF) * UNITS + m * 8);
            uint4 h3 = *(const uint4*)(hb + (size_t)(e3.x & 0xFFFFF) * UNITS + m * 8);
            __builtin_amdgcn_sched_barrier(0);
            float v0 = __int_as_float(e0.y);
            float v1 = __int_as_float(e1.y);
            float v2 = __int_as_float(e2.y);
            float v3 = __int_as_float(e3.y);
            ACC8(h0, v0)
            ACC8(h1, v1)
            ACC8(h2, v2)
            ACC8(h3, v3)
            j += 4;
        }
        for (; j < c; ++j) {
            int2 e0 = sbuf[start + j];
            uint4 h0 = *(const uint4*)(hb + (size_t)(e0.x & 0xFFFFF) * UNITS + m * 8);
            float v0 = __int_as_float(e0.y);
            ACC8(h0, v0)
        }

        float* op = out + (size_t)dg * UNITS + m * 8;
        *(floatx4*)op       = (floatx4){a0, a1, a2, a3};
        *(floatx4*)(op + 4) = (floatx4){a4, a5, a6, a7};
    }
}

extern "C" void kernel_launch(void* const* d_in, const int* in_sizes, int n_in,
                              void* d_out, int out_size, void* d_ws, size_t ws_size,
                              hipStream_t stream) {
    const float* x        = (const float*)d_in[0];
    const float* w        = (const float*)d_in[1];
    const int*   adj_src  = (const int*)d_in[2];
    const int*   adj_dst  = (const int*)d_in[3];
    const float* adj_vals = (const float*)d_in[4];
    float*       out      = (float*)d_out;

    const int M = in_sizes[0] / D_FEAT;   // 100000 nodes
    const int E = in_sizes[2];            // 1600000 edges
    const int NB = (M + BINSZ - 1) >> NBITS;   // 782 coarse bins

    // Workspace:
    //   hb:     M*128*2           = 25.6 MB
    //   wT:     128*256*2         = 64 KB
    //   cursor: NB*4 ints         = 12.5 KB
    //   staged: NB*BINCAP*8       = 15.2 MB
    char*   ws  = (char*)d_ws;
    ushort* hb  = (ushort*)ws;
    size_t  off = (size_t)M * UNITS * sizeof(ushort);
    off = (off + 255) & ~(size_t)255;
    ushort* wT  = (ushort*)(ws + off);
    off += (size_t)128 * 256 * sizeof(ushort);
    int*    cursor = (int*)(ws + off);
    off += (size_t)NB * 4 * sizeof(int);
    off = (off + 15) & ~(size_t)15;
    int2*   staged = (int2*)(ws + off);

    wt_prep_kernel<<<128, 256, 0, stream>>>(w, wT, cursor, NB * 4);

    gemm_mfma4_kernel<<<(M + 127) / 128, 512, 0, stream>>>(x, wT, hb, M);

    const int NSCAT = 256;
    const int chunk = (E + NSCAT - 1) / NSCAT;
    coarse_scatter_kernel<<<NSCAT, 1024, 0, stream>>>(adj_src, adj_dst, adj_vals,
                                                      cursor, staged, E, NB, chunk);

    gather_sort_kernel<<<NB, 512, 0, stream>>>(cursor, staged, hb, out, M);
}